// Round 1
// baseline (927.129 us; speedup 1.0000x reference)
//
#include <hip/hip_runtime.h>

#define NB 64
#define NS 256
#define ND 2048
#define NH 16
#define NHD 128

typedef unsigned short ushort_t;
typedef __attribute__((ext_vector_type(8))) __bf16 bf16x8;
typedef __attribute__((ext_vector_type(4))) short shortx4;
typedef __attribute__((ext_vector_type(4))) float f32x4;
typedef __attribute__((ext_vector_type(4))) unsigned short ushortx4;

__device__ __forceinline__ unsigned short f2bf(float f) {
  union { float f; unsigned int u; } v; v.f = f;
  unsigned int r = v.u + 0x7FFFu + ((v.u >> 16) & 1u);
  return (unsigned short)(r >> 16);
}

__device__ __forceinline__ void gload16(const void* g, void* l) {
  __builtin_amdgcn_global_load_lds(
      (__attribute__((address_space(1))) void*)(void*)(g),
      (__attribute__((address_space(3))) void*)(l), 16, 0, 0);
}

__global__ void cast_f32_bf16(const float* __restrict__ in, ushort_t* __restrict__ out, long n) {
  long i = ((long)blockIdx.x * blockDim.x + threadIdx.x) * 4;
  if (i + 3 < n) {
    float4 v = *reinterpret_cast<const float4*>(in + i);
    ushortx4 o;
    o.x = f2bf(v.x); o.y = f2bf(v.y); o.z = f2bf(v.z); o.w = f2bf(v.w);
    *reinterpret_cast<ushortx4*>(out + i) = o;
  }
}

// C[m,n] = sum_k A[m,k] * Bt[n,k]; A,Bt bf16 row-major K-contiguous.
// MODE 0: store fp32 C[m*N+n].  MODE 1: store bf16 permuted qkv [3][B][H][S][HD].
template<int MODE>
__global__ __launch_bounds__(256) void gemm_bt(const ushort_t* __restrict__ A,
                                               const ushort_t* __restrict__ Bt,
                                               float* __restrict__ Cf,
                                               ushort_t* __restrict__ Cq,
                                               int M, int N, int K) {
  __shared__ ushort_t As[128 * 32];
  __shared__ ushort_t Bs[128 * 32];
  const int tid = threadIdx.x;
  const int wave = tid >> 6, lane = tid & 63;
  const int wm = wave >> 1, wn = wave & 1;
  const int m0 = blockIdx.y * 128, n0 = blockIdx.x * 128;
  const int lr = lane >> 2;          // row within 16-row staging block
  const int lc = (lane & 3) * 8;     // col elem within 32
  const int l15 = lane & 15, lg = lane >> 4;
  f32x4 acc[4][4] = {};
  const int nkt = K / 32;
  for (int kt = 0; kt < nkt; ++kt) {
    const int k0 = kt * 32;
    #pragma unroll
    for (int c = 0; c < 2; ++c) {
      const int rowblk = (c * 4 + wave) * 16;
      gload16(A + (long)(m0 + rowblk + lr) * K + k0 + lc, As + rowblk * 32);
      gload16(Bt + (long)(n0 + rowblk + lr) * K + k0 + lc, Bs + rowblk * 32);
    }
    __syncthreads();
    bf16x8 af[4], bfr[4];
    #pragma unroll
    for (int i = 0; i < 4; ++i) {
      af[i]  = *reinterpret_cast<const bf16x8*>(As + (wm * 64 + i * 16 + l15) * 32 + lg * 8);
      bfr[i] = *reinterpret_cast<const bf16x8*>(Bs + (wn * 64 + i * 16 + l15) * 32 + lg * 8);
    }
    #pragma unroll
    for (int i = 0; i < 4; ++i)
      #pragma unroll
      for (int j = 0; j < 4; ++j)
        acc[i][j] = __builtin_amdgcn_mfma_f32_16x16x32_bf16(af[i], bfr[j], acc[i][j], 0, 0, 0);
    __syncthreads();
  }
  // epilogue: D layout col = lane&15, row = (lane>>4)*4 + r
  #pragma unroll
  for (int i = 0; i < 4; ++i)
    #pragma unroll
    for (int j = 0; j < 4; ++j) {
      const int n = n0 + wn * 64 + j * 16 + l15;
      #pragma unroll
      for (int r = 0; r < 4; ++r) {
        const int m = m0 + wm * 64 + i * 16 + lg * 4 + r;
        const float v = acc[i][j][r];
        if (MODE == 0) {
          Cf[(long)m * N + n] = v;
        } else {
          const int t = n >> 11, hh = (n >> 7) & 15, hd = n & 127;
          const int b = m >> 8, s = m & 255;
          const long idx = ((((long)t * NB + b) * NH + hh) * NS + s) * NHD + hd;
          Cq[idx] = f2bf(v);
        }
      }
    }
}

// One block per (b,h); 8 waves x 32 Q-rows. Flash-style online softmax.
// Computes St = K·Q^T (swapped operands) so St D-frags feed PV's B-operand
// (mfma 16x16x16bf16_1k) with zero cross-lane data movement. Accumulates O^T[hd][q].
__global__ __launch_bounds__(512) void attn_fused(const ushort_t* __restrict__ qkv,
                                                  ushort_t* __restrict__ ctx) {
  const int bh = blockIdx.x;
  const int b = bh >> 4, h = bh & 15;
  const int wave = threadIdx.x >> 6, lane = threadIdx.x & 63;
  const int l15 = lane & 15, lg = lane >> 4;
  const long head_off = ((long)(b * NH + h)) * (NS * NHD);
  const ushort_t* Qp = qkv + head_off;
  const ushort_t* Kp = qkv + (long)NB * NH * NS * NHD + head_off;
  const ushort_t* Vp = qkv + 2L * NB * NH * NS * NHD + head_off;
  const int q0 = wave * 32;

  bf16x8 qf[2][4];
  #pragma unroll
  for (int ni = 0; ni < 2; ++ni)
    #pragma unroll
    for (int kk = 0; kk < 4; ++kk)
      qf[ni][kk] = *reinterpret_cast<const bf16x8*>(Qp + (q0 + ni * 16 + l15) * NHD + kk * 32 + lg * 8);

  f32x4 o[8][2] = {};                  // O^T frag: hd = f*16 + lg*4 + r, q = q0 + ni*16 + l15
  float mstate[2] = {-1e30f, -1e30f};
  float lstate[2] = {0.f, 0.f};
  const float scale = 0.08838834764831845f;   // 128^-0.5
  const int ntiles = (q0 + 32 + 63) >> 6;

  for (int kt = 0; kt < ntiles; ++kt) {
    f32x4 st[4][2] = {};               // St frag: kv = kt*64 + mi*16 + lg*4 + r, q = q0 + ni*16 + l15
    #pragma unroll
    for (int kk = 0; kk < 4; ++kk) {
      bf16x8 kf[4];
      #pragma unroll
      for (int mi = 0; mi < 4; ++mi)
        kf[mi] = *reinterpret_cast<const bf16x8*>(Kp + (kt * 64 + mi * 16 + l15) * NHD + kk * 32 + lg * 8);
      #pragma unroll
      for (int mi = 0; mi < 4; ++mi)
        #pragma unroll
        for (int ni = 0; ni < 2; ++ni)
          st[mi][ni] = __builtin_amdgcn_mfma_f32_16x16x32_bf16(kf[mi], qf[ni][kk], st[mi][ni], 0, 0, 0);
    }
    const bool last = (kt == ntiles - 1);
    #pragma unroll
    for (int mi = 0; mi < 4; ++mi)
      #pragma unroll
      for (int ni = 0; ni < 2; ++ni)
        #pragma unroll
        for (int r = 0; r < 4; ++r) {
          const int kc = kt * 64 + mi * 16 + lg * 4 + r;
          const int q = q0 + ni * 16 + l15;
          float v = st[mi][ni][r] * scale;
          if (last && kc > q) v = -1e30f;
          st[mi][ni][r] = v;
        }
    shortx4 p[4][2];
    #pragma unroll
    for (int ni = 0; ni < 2; ++ni) {
      float tmax = -1e30f;
      #pragma unroll
      for (int mi = 0; mi < 4; ++mi)
        #pragma unroll
        for (int r = 0; r < 4; ++r) tmax = fmaxf(tmax, st[mi][ni][r]);
      tmax = fmaxf(tmax, __shfl_xor(tmax, 16, 64));
      tmax = fmaxf(tmax, __shfl_xor(tmax, 32, 64));
      const float mnew = fmaxf(mstate[ni], tmax);
      const float alpha = __expf(mstate[ni] - mnew);
      float tsum = 0.f;
      #pragma unroll
      for (int mi = 0; mi < 4; ++mi)
        #pragma unroll
        for (int r = 0; r < 4; ++r) {
          const float pe = __expf(st[mi][ni][r] - mnew);
          st[mi][ni][r] = pe;
          tsum += pe;
        }
      tsum += __shfl_xor(tsum, 16, 64);
      tsum += __shfl_xor(tsum, 32, 64);
      lstate[ni] = lstate[ni] * alpha + tsum;
      mstate[ni] = mnew;
      #pragma unroll
      for (int f = 0; f < 8; ++f)
        #pragma unroll
        for (int r = 0; r < 4; ++r) o[f][ni][r] *= alpha;
      #pragma unroll
      for (int mi = 0; mi < 4; ++mi)
        #pragma unroll
        for (int r = 0; r < 4; ++r) p[mi][ni][r] = (short)f2bf(st[mi][ni][r]);
    }
    // PV: O^T[hd][q] += V^T · P   (A = V^T gather, B = P frags in-place)
    #pragma unroll
    for (int f = 0; f < 8; ++f)
      #pragma unroll
      for (int mi = 0; mi < 4; ++mi) {
        shortx4 vt;
        #pragma unroll
        for (int j = 0; j < 4; ++j)
          vt[j] = (short)Vp[(kt * 64 + mi * 16 + lg * 4 + j) * NHD + f * 16 + l15];
        #pragma unroll
        for (int ni = 0; ni < 2; ++ni)
          o[f][ni] = __builtin_amdgcn_mfma_f32_16x16x16bf16_1k(vt, p[mi][ni], o[f][ni], 0, 0, 0);
      }
  }
  const float inv0 = 1.f / lstate[0], inv1 = 1.f / lstate[1];
  #pragma unroll
  for (int f = 0; f < 8; ++f)
    #pragma unroll
    for (int ni = 0; ni < 2; ++ni) {
      const float inv = ni ? inv1 : inv0;
      const int q = q0 + ni * 16 + l15;
      const int hd = f * 16 + lg * 4;
      ushortx4 ov;
      #pragma unroll
      for (int r = 0; r < 4; ++r) ov[r] = f2bf(o[f][ni][r] * inv);
      *reinterpret_cast<ushortx4*>(ctx + ((long)(b * NS + q)) * ND + h * NHD + hd) = ov;
    }
}

extern "C" void kernel_launch(void* const* d_in, const int* in_sizes, int n_in,
                              void* d_out, int out_size, void* d_ws, size_t ws_size,
                              hipStream_t stream) {
  const float* x     = (const float*)d_in[0];
  const float* w_qkv = (const float*)d_in[1];
  const float* w_o   = (const float*)d_in[2];
  char* ws = (char*)d_ws;
  // layout (bytes): xb 67108864 | wqkvb 25165824 | wob 8388608 | qkvb 201326592 | ctxb 67108864
  if (ws_size < 369098752UL) return;  // fail loudly (output stays zero) rather than corrupt
  ushort_t* xb    = (ushort_t*)(ws);
  ushort_t* wqkvb = (ushort_t*)(ws + 67108864L);
  ushort_t* wob   = (ushort_t*)(ws + 92274688L);
  ushort_t* qkvb  = (ushort_t*)(ws + 100663296L);
  ushort_t* ctxb  = (ushort_t*)(ws + 301989888L);

  const long nx = (long)NB * NS * ND;        // 33554432
  const long nq = 3L * ND * ND;              // 12582912
  const long no = (long)ND * ND;             // 4194304
  cast_f32_bf16<<<dim3(nx / 1024), 256, 0, stream>>>(x, xb, nx);
  cast_f32_bf16<<<dim3(nq / 1024), 256, 0, stream>>>(w_qkv, wqkvb, nq);
  cast_f32_bf16<<<dim3(no / 1024), 256, 0, stream>>>(w_o, wob, no);

  // qkv = x @ w_qkv^T  -> permuted bf16 [3][B][H][S][HD]
  gemm_bt<1><<<dim3(48, 128), 256, 0, stream>>>(xb, wqkvb, nullptr, qkvb, NB * NS, 3 * ND, ND);
  // fused causal attention -> ctx bf16 [B][S][D]
  attn_fused<<<dim3(NB * NH), 512, 0, stream>>>(qkvb, ctxb);
  // out = ctx @ w_o^T  (fp32)
  gemm_bt<0><<<dim3(16, 128), 256, 0, stream>>>(ctxb, wob, (float*)d_out, nullptr, NB * NS, ND, ND);
}

// Round 2
// 707.046 us; speedup vs baseline: 1.3113x; 1.3113x over previous
//
#include <hip/hip_runtime.h>

#define NB 64
#define NS 256
#define ND 2048
#define NH 16
#define NHD 128

typedef unsigned short ushort_t;
typedef __attribute__((ext_vector_type(8))) __bf16 bf16x8;
typedef __attribute__((ext_vector_type(4))) short shortx4;
typedef __attribute__((ext_vector_type(4))) float f32x4;
typedef __attribute__((ext_vector_type(4))) unsigned short ushortx4;

__device__ __forceinline__ unsigned short f2bf(float f) {
  union { float f; unsigned int u; } v; v.f = f;
  unsigned int r = v.u + 0x7FFFu + ((v.u >> 16) & 1u);
  return (unsigned short)(r >> 16);
}

__device__ __forceinline__ void gload16(const void* g, void* l) {
  __builtin_amdgcn_global_load_lds(
      (__attribute__((address_space(1))) void*)(void*)(g),
      (__attribute__((address_space(3))) void*)(l), 16, 0, 0);
}

__global__ void cast_f32_bf16(const float* __restrict__ in, ushort_t* __restrict__ out, long n) {
  long i = ((long)blockIdx.x * blockDim.x + threadIdx.x) * 4;
  if (i + 3 < n) {
    float4 v = *reinterpret_cast<const float4*>(in + i);
    ushortx4 o;
    o.x = f2bf(v.x); o.y = f2bf(v.y); o.z = f2bf(v.z); o.w = f2bf(v.w);
    *reinterpret_cast<ushortx4*>(out + i) = o;
  }
}

// ---------------------------------------------------------------------------
// 256x256 tile GEMM, BK=32, 8 waves (2M x 4N), 3-buffer LDS pipeline with
// counted vmcnt (T3+T4), T2 XOR swizzle (64B rows: colbyte ^= ((row>>1)&3)<<4,
// applied as inverse-swizzled global source + swizzled ds_read; LDS dest of
// global_load_lds stays linear per rule #21), T5 setprio around MFMA clusters,
// T1 bijective XCD block swizzle.
// C[m,n] = sum_k A[m,k]*Bt[n,k].  MODE 0: fp32 C.  MODE 1: bf16 permuted qkv.
// Pipeline: while computing K-tile t from buf[t%3], stage tile t+2 into
// buf[(t+2)%3] (A in phase 1, B in phase 2; 2 global_load_lds each).
// End-of-tile wait: vmcnt(4) (leaves t+2's 4 loads in flight), vmcnt(0) only
// in the 2-tile tail.  LDS = 3 * (16KB A + 16KB B) = 96 KiB (dynamic).
// ---------------------------------------------------------------------------
template<int MODE>
__global__ __launch_bounds__(512, 2) void gemm256(const ushort_t* __restrict__ A,
                                                  const ushort_t* __restrict__ Bt,
                                                  float* __restrict__ Cf,
                                                  ushort_t* __restrict__ Cq,
                                                  int M, int N, int K) {
  extern __shared__ char smem[];   // 3 bufs * 32768B; A at +0, B at +16384 in each buf
  const int tid = threadIdx.x;
  const int wv = tid >> 6, lane = tid & 63;
  const int l15 = lane & 15, lg = lane >> 4;
  const int wm = wv >> 2, wn = wv & 3;     // 2 x 4 wave grid; wave tile 128x64

  // T1: bijective XCD-aware block swizzle
  const int nbn = N >> 8;
  const int nwg = (M >> 8) * nbn;
  const int bid = blockIdx.x;
  const int q8 = nwg >> 3, r8 = nwg & 7;
  const int xcd = bid & 7, lin = bid >> 3;
  const int wg = (xcd < r8 ? xcd * (q8 + 1) : r8 * (q8 + 1) + (xcd - r8) * q8) + lin;
  const int m0 = (wg / nbn) << 8;
  const int n0 = (wg % nbn) << 8;

  // staging source (per-lane, pre-swizzled).  Linear LDS slot of this lane:
  // row = wv*16 + lane/4 (within 128-row half), colbyte = (lane&3)*16.
  // Logical elem at that slot has col ^= ((row>>1)&3)<<4 bytes (involution).
  const int srow = wv * 16 + (lane >> 2);
  const int sce = ((lane & 3) * 8) ^ (((srow >> 1) & 3) << 3);  // elems
  const ushort_t* pa0 = A  + (long)(m0 + srow) * K + sce;        // rows 0..127
  const ushort_t* pa1 = pa0 + (long)128 * K;                     // rows 128..255
  const ushort_t* pb0 = Bt + (long)(n0 + srow) * K + sce;
  const ushort_t* pb1 = pb0 + (long)128 * K;

  // ds_read byte-XOR constant (row bits 1..2 == l15 bits 1..2 for all frags)
  const int c = (lg * 16) ^ (((l15 >> 1) & 3) << 4);

  f32x4 acc[8][4] = {};
  const int nkt = K >> 5;

  // prologue: stage tiles 0 -> buf0, 1 -> buf1 (4 loads each)
  {
    char* d0 = smem + wv * 1024;
    gload16(pa0, d0);
    gload16(pa1, d0 + 8192);
    gload16(pb0, d0 + 16384);
    gload16(pb1, d0 + 16384 + 8192);
    char* d1 = smem + 32768 + wv * 1024;
    gload16(pa0 + 32, d1);
    gload16(pa1 + 32, d1 + 8192);
    gload16(pb0 + 32, d1 + 16384);
    gload16(pb1 + 32, d1 + 16384 + 8192);
  }
  asm volatile("s_waitcnt vmcnt(4)" ::: "memory");   // tile 0 landed; tile 1 in flight
  __builtin_amdgcn_s_barrier();

  int buf = 0;
  for (int t = 0; t < nkt; ++t) {
    const int so = buf * 32768;
    const bool pf = (t + 2 < nkt);
    const int pb = (buf + 2 >= 3) ? buf - 1 : buf + 2;
    // ---- phase 1: ds_read A(rows 0-63 of wave) + all B; stage A of t+2 ----
    bf16x8 af[4], bfr[4];
    #pragma unroll
    for (int i = 0; i < 4; ++i)
      af[i] = *reinterpret_cast<const bf16x8*>(smem + so + (wm * 128 + i * 16 + l15) * 64 + c);
    #pragma unroll
    for (int j = 0; j < 4; ++j)
      bfr[j] = *reinterpret_cast<const bf16x8*>(smem + so + 16384 + (wn * 64 + j * 16 + l15) * 64 + c);
    if (pf) {
      char* d = smem + pb * 32768 + wv * 1024;
      gload16(pa0 + (t + 2) * 32, d);
      gload16(pa1 + (t + 2) * 32, d + 8192);
    }
    __builtin_amdgcn_s_barrier();
    asm volatile("s_waitcnt lgkmcnt(0)" ::: "memory");
    __builtin_amdgcn_sched_barrier(0);
    __builtin_amdgcn_s_setprio(1);
    #pragma unroll
    for (int i = 0; i < 4; ++i)
      #pragma unroll
      for (int j = 0; j < 4; ++j)
        acc[i][j] = __builtin_amdgcn_mfma_f32_16x16x32_bf16(af[i], bfr[j], acc[i][j], 0, 0, 0);
    __builtin_amdgcn_s_setprio(0);
    __builtin_amdgcn_s_barrier();
    // ---- phase 2: ds_read A(rows 64-127 of wave); stage B of t+2 ----
    bf16x8 ag[4];
    #pragma unroll
    for (int i = 0; i < 4; ++i)
      ag[i] = *reinterpret_cast<const bf16x8*>(smem + so + (wm * 128 + 64 + i * 16 + l15) * 64 + c);
    if (pf) {
      char* d = smem + pb * 32768 + 16384 + wv * 1024;
      gload16(pb0 + (t + 2) * 32, d);
      gload16(pb1 + (t + 2) * 32, d + 8192);
    }
    __builtin_amdgcn_s_barrier();
    asm volatile("s_waitcnt lgkmcnt(0)" ::: "memory");
    __builtin_amdgcn_sched_barrier(0);
    __builtin_amdgcn_s_setprio(1);
    #pragma unroll
    for (int i = 0; i < 4; ++i)
      #pragma unroll
      for (int j = 0; j < 4; ++j)
        acc[4 + i][j] = __builtin_amdgcn_mfma_f32_16x16x32_bf16(ag[i], bfr[j], acc[4 + i][j], 0, 0, 0);
    __builtin_amdgcn_s_setprio(0);
    if (pf) asm volatile("s_waitcnt vmcnt(4)" ::: "memory");  // t+1 landed; t+2 in flight
    else    asm volatile("s_waitcnt vmcnt(0)" ::: "memory");  // tail drain
    __builtin_amdgcn_s_barrier();
    buf = (buf + 1 == 3) ? 0 : buf + 1;
  }

  // epilogue: D frag col = l15 (n), rows = lg*4 + r
  #pragma unroll
  for (int k = 0; k < 8; ++k) {
    const int mrow = m0 + wm * 128 + (k >> 2) * 64 + (k & 3) * 16 + lg * 4;
    #pragma unroll
    for (int j = 0; j < 4; ++j) {
      const int n = n0 + wn * 64 + j * 16 + l15;
      #pragma unroll
      for (int r = 0; r < 4; ++r) {
        const int m = mrow + r;
        const float v = acc[k][j][r];
        if (MODE == 0) {
          Cf[(long)m * N + n] = v;
        } else {
          const int tq = n >> 11, hh = (n >> 7) & 15, hd = n & 127;
          const int b = m >> 8, s = m & 255;
          Cq[((((long)tq * NB + b) * NH + hh) * NS + s) * NHD + hd] = f2bf(v);
        }
      }
    }
  }
}

// One block per (b,h); 8 waves x 32 Q-rows. Flash-style online softmax.
__global__ __launch_bounds__(512) void attn_fused(const ushort_t* __restrict__ qkv,
                                                  ushort_t* __restrict__ ctx) {
  const int bh = blockIdx.x;
  const int b = bh >> 4, h = bh & 15;
  const int wave = threadIdx.x >> 6, lane = threadIdx.x & 63;
  const int l15 = lane & 15, lg = lane >> 4;
  const long head_off = ((long)(b * NH + h)) * (NS * NHD);
  const ushort_t* Qp = qkv + head_off;
  const ushort_t* Kp = qkv + (long)NB * NH * NS * NHD + head_off;
  const ushort_t* Vp = qkv + 2L * NB * NH * NS * NHD + head_off;
  const int q0 = wave * 32;

  bf16x8 qf[2][4];
  #pragma unroll
  for (int ni = 0; ni < 2; ++ni)
    #pragma unroll
    for (int kk = 0; kk < 4; ++kk)
      qf[ni][kk] = *reinterpret_cast<const bf16x8*>(Qp + (q0 + ni * 16 + l15) * NHD + kk * 32 + lg * 8);

  f32x4 o[8][2] = {};
  float mstate[2] = {-1e30f, -1e30f};
  float lstate[2] = {0.f, 0.f};
  const float scale = 0.08838834764831845f;
  const int ntiles = (q0 + 32 + 63) >> 6;

  for (int kt = 0; kt < ntiles; ++kt) {
    f32x4 st[4][2] = {};
    #pragma unroll
    for (int kk = 0; kk < 4; ++kk) {
      bf16x8 kf[4];
      #pragma unroll
      for (int mi = 0; mi < 4; ++mi)
        kf[mi] = *reinterpret_cast<const bf16x8*>(Kp + (kt * 64 + mi * 16 + l15) * NHD + kk * 32 + lg * 8);
      #pragma unroll
      for (int mi = 0; mi < 4; ++mi)
        #pragma unroll
        for (int ni = 0; ni < 2; ++ni)
          st[mi][ni] = __builtin_amdgcn_mfma_f32_16x16x32_bf16(kf[mi], qf[ni][kk], st[mi][ni], 0, 0, 0);
    }
    const bool last = (kt == ntiles - 1);
    #pragma unroll
    for (int mi = 0; mi < 4; ++mi)
      #pragma unroll
      for (int ni = 0; ni < 2; ++ni)
        #pragma unroll
        for (int r = 0; r < 4; ++r) {
          const int kc = kt * 64 + mi * 16 + lg * 4 + r;
          const int q = q0 + ni * 16 + l15;
          float v = st[mi][ni][r] * scale;
          if (last && kc > q) v = -1e30f;
          st[mi][ni][r] = v;
        }
    shortx4 p[4][2];
    #pragma unroll
    for (int ni = 0; ni < 2; ++ni) {
      float tmax = -1e30f;
      #pragma unroll
      for (int mi = 0; mi < 4; ++mi)
        #pragma unroll
        for (int r = 0; r < 4; ++r) tmax = fmaxf(tmax, st[mi][ni][r]);
      tmax = fmaxf(tmax, __shfl_xor(tmax, 16, 64));
      tmax = fmaxf(tmax, __shfl_xor(tmax, 32, 64));
      const float mnew = fmaxf(mstate[ni], tmax);
      const float alpha = __expf(mstate[ni] - mnew);
      float tsum = 0.f;
      #pragma unroll
      for (int mi = 0; mi < 4; ++mi)
        #pragma unroll
        for (int r = 0; r < 4; ++r) {
          const float pe = __expf(st[mi][ni][r] - mnew);
          st[mi][ni][r] = pe;
          tsum += pe;
        }
      tsum += __shfl_xor(tsum, 16, 64);
      tsum += __shfl_xor(tsum, 32, 64);
      lstate[ni] = lstate[ni] * alpha + tsum;
      mstate[ni] = mnew;
      #pragma unroll
      for (int f = 0; f < 8; ++f)
        #pragma unroll
        for (int r = 0; r < 4; ++r) o[f][ni][r] *= alpha;
      #pragma unroll
      for (int mi = 0; mi < 4; ++mi)
        #pragma unroll
        for (int r = 0; r < 4; ++r) p[mi][ni][r] = (short)f2bf(st[mi][ni][r]);
    }
    #pragma unroll
    for (int f = 0; f < 8; ++f)
      #pragma unroll
      for (int mi = 0; mi < 4; ++mi) {
        shortx4 vt;
        #pragma unroll
        for (int j = 0; j < 4; ++j)
          vt[j] = (short)Vp[(kt * 64 + mi * 16 + lg * 4 + j) * NHD + f * 16 + l15];
        #pragma unroll
        for (int ni = 0; ni < 2; ++ni)
          o[f][ni] = __builtin_amdgcn_mfma_f32_16x16x16bf16_1k(vt, p[mi][ni], o[f][ni], 0, 0, 0);
      }
  }
  const float inv0 = 1.f / lstate[0], inv1 = 1.f / lstate[1];
  #pragma unroll
  for (int f = 0; f < 8; ++f)
    #pragma unroll
    for (int ni = 0; ni < 2; ++ni) {
      const float inv = ni ? inv1 : inv0;
      const int q = q0 + ni * 16 + l15;
      const int hd = f * 16 + lg * 4;
      ushortx4 ov;
      #pragma unroll
      for (int r = 0; r < 4; ++r) ov[r] = f2bf(o[f][ni][r] * inv);
      *reinterpret_cast<ushortx4*>(ctx + ((long)(b * NS + q)) * ND + h * NHD + hd) = ov;
    }
}

extern "C" void kernel_launch(void* const* d_in, const int* in_sizes, int n_in,
                              void* d_out, int out_size, void* d_ws, size_t ws_size,
                              hipStream_t stream) {
  const float* x     = (const float*)d_in[0];
  const float* w_qkv = (const float*)d_in[1];
  const float* w_o   = (const float*)d_in[2];
  char* ws = (char*)d_ws;
  if (ws_size < 369098752UL) return;
  ushort_t* xb    = (ushort_t*)(ws);
  ushort_t* wqkvb = (ushort_t*)(ws + 67108864L);
  ushort_t* wob   = (ushort_t*)(ws + 92274688L);
  ushort_t* qkvb  = (ushort_t*)(ws + 100663296L);
  ushort_t* ctxb  = (ushort_t*)(ws + 301989888L);

  const long nx = (long)NB * NS * ND;
  const long nq = 3L * ND * ND;
  const long no = (long)ND * ND;
  cast_f32_bf16<<<dim3(nx / 1024), 256, 0, stream>>>(x, xb, nx);
  cast_f32_bf16<<<dim3(nq / 1024), 256, 0, stream>>>(w_qkv, wqkvb, nq);
  cast_f32_bf16<<<dim3(no / 1024), 256, 0, stream>>>(w_o, wob, no);

  const int lds_bytes = 3 * 32768;  // 96 KiB
  (void)hipFuncSetAttribute(reinterpret_cast<const void*>(&gemm256<1>),
                            hipFuncAttributeMaxDynamicSharedMemorySize, lds_bytes);
  (void)hipFuncSetAttribute(reinterpret_cast<const void*>(&gemm256<0>),
                            hipFuncAttributeMaxDynamicSharedMemorySize, lds_bytes);

  // qkv = x @ w_qkv^T  -> permuted bf16 [3][B][H][S][HD]
  gemm256<1><<<dim3(64 * 24), 512, lds_bytes, stream>>>(xb, wqkvb, nullptr, qkvb,
                                                        NB * NS, 3 * ND, ND);
  // fused causal attention -> ctx bf16 [B][S][D]
  attn_fused<<<dim3(NB * NH), 512, 0, stream>>>(qkvb, ctxb);
  // out = ctx @ w_o^T  (fp32)
  gemm256<0><<<dim3(64 * 8), 512, lds_bytes, stream>>>(ctxb, wob, (float*)d_out, nullptr,
                                                       NB * NS, ND, ND);
}

// Round 3
// 705.888 us; speedup vs baseline: 1.3134x; 1.0016x over previous
//
#include <hip/hip_runtime.h>

#define NB 64
#define NS 256
#define ND 2048
#define NH 16
#define NHD 128

typedef unsigned short ushort_t;
typedef __attribute__((ext_vector_type(8))) __bf16 bf16x8;
typedef __attribute__((ext_vector_type(4))) short shortx4;
typedef __attribute__((ext_vector_type(4))) float f32x4;
typedef __attribute__((ext_vector_type(4))) unsigned short ushortx4;

__device__ __forceinline__ unsigned short f2bf(float f) {
  union { float f; unsigned int u; } v; v.f = f;
  unsigned int r = v.u + 0x7FFFu + ((v.u >> 16) & 1u);
  return (unsigned short)(r >> 16);
}

__device__ __forceinline__ void gload16(const void* g, void* l) {
  __builtin_amdgcn_global_load_lds(
      (__attribute__((address_space(1))) void*)(void*)(g),
      (__attribute__((address_space(3))) void*)(l), 16, 0, 0);
}

__global__ void cast_f32_bf16(const float* __restrict__ in, ushort_t* __restrict__ out, long n) {
  long i = ((long)blockIdx.x * blockDim.x + threadIdx.x) * 4;
  if (i + 3 < n) {
    float4 v = *reinterpret_cast<const float4*>(in + i);
    ushortx4 o;
    o.x = f2bf(v.x); o.y = f2bf(v.y); o.z = f2bf(v.z); o.w = f2bf(v.w);
    *reinterpret_cast<ushortx4*>(out + i) = o;
  }
}

// ---------------------------------------------------------------------------
// 256x256 tile GEMM, BK=32, 8 waves (2M x 4N), register-pipelined tile loop:
//   4 LDS buffers (128 KiB), frag regs double-buffered (FA/FB, unroll x2).
//   Per tile: 1 barrier; stage tile t+3 (4 gload16); issue 12 ds_read_b128
//   for F(t+1) from buf(t+1); lgkmcnt(12) -> only tile t's older reads drain,
//   new reads overlap the 32-MFMA cluster; vmcnt(4) keeps stage(t+3) in
//   flight across the barrier (counted, never 0 in steady state).
// T2 XOR swizzle (inverse-swizzled global source, swizzled ds_read, linear
// gload_lds dest); T5 setprio; T1 bijective XCD block swizzle.
// C[m,n] = sum_k A[m,k]*Bt[n,k].  MODE 0: fp32 C.  MODE 1: bf16 permuted qkv.
// ---------------------------------------------------------------------------
template<int MODE>
__global__ __launch_bounds__(512, 2) void gemm256(const ushort_t* __restrict__ A,
                                                  const ushort_t* __restrict__ Bt,
                                                  float* __restrict__ Cf,
                                                  ushort_t* __restrict__ Cq,
                                                  int M, int N, int K) {
  extern __shared__ char smem[];   // 4 bufs * 32768B; A at +0 (16KB), B at +16384
  const int tid = threadIdx.x;
  const int wv = tid >> 6, lane = tid & 63;
  const int l15 = lane & 15, lg = lane >> 4;
  const int wm = wv >> 2, wn = wv & 3;     // 2 x 4 wave grid; wave tile 128x64

  // T1: bijective XCD-aware block swizzle
  const int nbn = N >> 8;
  const int nwg = (M >> 8) * nbn;
  const int bid = blockIdx.x;
  const int q8 = nwg >> 3, r8 = nwg & 7;
  const int xcd = bid & 7, lin = bid >> 3;
  const int wg = (xcd < r8 ? xcd * (q8 + 1) : r8 * (q8 + 1) + (xcd - r8) * q8) + lin;
  const int m0 = (wg / nbn) << 8;
  const int n0 = (wg % nbn) << 8;

  // staging source (per-lane, pre-swizzled; LDS dest stays linear)
  const int srow = wv * 16 + (lane >> 2);
  const int sce = ((lane & 3) * 8) ^ (((srow >> 1) & 3) << 3);  // elems
  const ushort_t* pa0 = A  + (long)(m0 + srow) * K + sce;        // rows 0..127
  const ushort_t* pa1 = pa0 + (long)128 * K;                     // rows 128..255
  const ushort_t* pb0 = Bt + (long)(n0 + srow) * K + sce;
  const ushort_t* pb1 = pb0 + (long)128 * K;

  // ds_read byte-XOR constant
  const int c = (lg * 16) ^ (((l15 >> 1) & 3) << 4);

  f32x4 acc[8][4] = {};
  const int nkt = K >> 5;          // assumes nkt >= 4 and even (K=2048 -> 64)

  bf16x8 faA[8], faB[4], fbA[8], fbB[4];

  // prologue: stage tiles 0,1,2 -> bufs 0,1,2
  #pragma unroll
  for (int tt = 0; tt < 3; ++tt) {
    char* d = smem + tt * 32768 + wv * 1024;
    const long ko = (long)tt * 32;
    gload16(pa0 + ko, d);
    gload16(pa1 + ko, d + 8192);
    gload16(pb0 + ko, d + 16384);
    gload16(pb1 + ko, d + 24576);
  }
  asm volatile("s_waitcnt vmcnt(8)" ::: "memory");   // buf0 landed
  __builtin_amdgcn_s_barrier();
  __builtin_amdgcn_sched_barrier(0);
  #pragma unroll
  for (int i = 0; i < 8; ++i)
    faA[i] = *reinterpret_cast<const bf16x8*>(smem + (wm * 128 + i * 16 + l15) * 64 + c);
  #pragma unroll
  for (int j = 0; j < 4; ++j)
    faB[j] = *reinterpret_cast<const bf16x8*>(smem + 16384 + (wn * 64 + j * 16 + l15) * 64 + c);
  asm volatile("s_waitcnt vmcnt(4)" ::: "memory");   // buf1 landed (buf2 in flight)

#define TILE(T_, CA_, CB_, NA_, NB_)                                           \
  {                                                                            \
    const int t_ = (T_);                                                       \
    __builtin_amdgcn_s_barrier();                                              \
    __builtin_amdgcn_sched_barrier(0);                                         \
    if (t_ + 3 < nkt) {                                                        \
      char* d = smem + ((t_ + 3) & 3) * 32768 + wv * 1024;                     \
      const long ko = (long)(t_ + 3) * 32;                                     \
      gload16(pa0 + ko, d);                                                    \
      gload16(pa1 + ko, d + 8192);                                             \
      gload16(pb0 + ko, d + 16384);                                            \
      gload16(pb1 + ko, d + 24576);                                            \
    }                                                                          \
    if (t_ + 1 < nkt) {                                                        \
      const char* rb = smem + ((t_ + 1) & 3) * 32768;                          \
      _Pragma("unroll")                                                        \
      for (int i = 0; i < 8; ++i)                                              \
        NA_[i] = *reinterpret_cast<const bf16x8*>(rb + (wm * 128 + i * 16 + l15) * 64 + c); \
      _Pragma("unroll")                                                        \
      for (int j = 0; j < 4; ++j)                                              \
        NB_[j] = *reinterpret_cast<const bf16x8*>(rb + 16384 + (wn * 64 + j * 16 + l15) * 64 + c); \
      asm volatile("s_waitcnt lgkmcnt(12)" ::: "memory");                      \
    } else {                                                                   \
      asm volatile("s_waitcnt lgkmcnt(0)" ::: "memory");                       \
    }                                                                          \
    __builtin_amdgcn_sched_barrier(0);                                         \
    __builtin_amdgcn_s_setprio(1);                                             \
    _Pragma("unroll")                                                          \
    for (int i = 0; i < 8; ++i)                                                \
      _Pragma("unroll")                                                        \
      for (int j = 0; j < 4; ++j)                                              \
        acc[i][j] = __builtin_amdgcn_mfma_f32_16x16x32_bf16(CA_[i], CB_[j], acc[i][j], 0, 0, 0); \
    __builtin_amdgcn_s_setprio(0);                                             \
    __builtin_amdgcn_sched_barrier(0);                                         \
    if (t_ + 3 < nkt) asm volatile("s_waitcnt vmcnt(4)" ::: "memory");         \
    else              asm volatile("s_waitcnt vmcnt(0)" ::: "memory");         \
  }

  for (int t = 0; t < nkt; t += 2) {
    TILE(t,     faA, faB, fbA, fbB);
    TILE(t + 1, fbA, fbB, faA, faB);
  }
#undef TILE

  // epilogue: D frag col = l15 (n), rows = lg*4 + r
  #pragma unroll
  for (int k = 0; k < 8; ++k) {
    const int mrow = m0 + wm * 128 + k * 16 + lg * 4;
    #pragma unroll
    for (int j = 0; j < 4; ++j) {
      const int n = n0 + wn * 64 + j * 16 + l15;
      #pragma unroll
      for (int r = 0; r < 4; ++r) {
        const int m = mrow + r;
        const float v = acc[k][j][r];
        if (MODE == 0) {
          Cf[(long)m * N + n] = v;
        } else {
          const int tq = n >> 11, hh = (n >> 7) & 15, hd = n & 127;
          const int b = m >> 8, s = m & 255;
          Cq[((((long)tq * NB + b) * NH + hh) * NS + s) * NHD + hd] = f2bf(v);
        }
      }
    }
  }
}

// One block per (b,h); 8 waves x 32 Q-rows. Flash-style online softmax.
__global__ __launch_bounds__(512) void attn_fused(const ushort_t* __restrict__ qkv,
                                                  ushort_t* __restrict__ ctx) {
  const int bh = blockIdx.x;
  const int b = bh >> 4, h = bh & 15;
  const int wave = threadIdx.x >> 6, lane = threadIdx.x & 63;
  const int l15 = lane & 15, lg = lane >> 4;
  const long head_off = ((long)(b * NH + h)) * (NS * NHD);
  const ushort_t* Qp = qkv + head_off;
  const ushort_t* Kp = qkv + (long)NB * NH * NS * NHD + head_off;
  const ushort_t* Vp = qkv + 2L * NB * NH * NS * NHD + head_off;
  const int q0 = wave * 32;

  bf16x8 qf[2][4];
  #pragma unroll
  for (int ni = 0; ni < 2; ++ni)
    #pragma unroll
    for (int kk = 0; kk < 4; ++kk)
      qf[ni][kk] = *reinterpret_cast<const bf16x8*>(Qp + (q0 + ni * 16 + l15) * NHD + kk * 32 + lg * 8);

  f32x4 o[8][2] = {};
  float mstate[2] = {-1e30f, -1e30f};
  float lstate[2] = {0.f, 0.f};
  const float scale = 0.08838834764831845f;
  const int ntiles = (q0 + 32 + 63) >> 6;

  for (int kt = 0; kt < ntiles; ++kt) {
    f32x4 st[4][2] = {};
    #pragma unroll
    for (int kk = 0; kk < 4; ++kk) {
      bf16x8 kf[4];
      #pragma unroll
      for (int mi = 0; mi < 4; ++mi)
        kf[mi] = *reinterpret_cast<const bf16x8*>(Kp + (kt * 64 + mi * 16 + l15) * NHD + kk * 32 + lg * 8);
      #pragma unroll
      for (int mi = 0; mi < 4; ++mi)
        #pragma unroll
        for (int ni = 0; ni < 2; ++ni)
          st[mi][ni] = __builtin_amdgcn_mfma_f32_16x16x32_bf16(kf[mi], qf[ni][kk], st[mi][ni], 0, 0, 0);
    }
    const bool last = (kt == ntiles - 1);
    #pragma unroll
    for (int mi = 0; mi < 4; ++mi)
      #pragma unroll
      for (int ni = 0; ni < 2; ++ni)
        #pragma unroll
        for (int r = 0; r < 4; ++r) {
          const int kc = kt * 64 + mi * 16 + lg * 4 + r;
          const int q = q0 + ni * 16 + l15;
          float v = st[mi][ni][r] * scale;
          if (last && kc > q) v = -1e30f;
          st[mi][ni][r] = v;
        }
    shortx4 p[4][2];
    #pragma unroll
    for (int ni = 0; ni < 2; ++ni) {
      float tmax = -1e30f;
      #pragma unroll
      for (int mi = 0; mi < 4; ++mi)
        #pragma unroll
        for (int r = 0; r < 4; ++r) tmax = fmaxf(tmax, st[mi][ni][r]);
      tmax = fmaxf(tmax, __shfl_xor(tmax, 16, 64));
      tmax = fmaxf(tmax, __shfl_xor(tmax, 32, 64));
      const float mnew = fmaxf(mstate[ni], tmax);
      const float alpha = __expf(mstate[ni] - mnew);
      float tsum = 0.f;
      #pragma unroll
      for (int mi = 0; mi < 4; ++mi)
        #pragma unroll
        for (int r = 0; r < 4; ++r) {
          const float pe = __expf(st[mi][ni][r] - mnew);
          st[mi][ni][r] = pe;
          tsum += pe;
        }
      tsum += __shfl_xor(tsum, 16, 64);
      tsum += __shfl_xor(tsum, 32, 64);
      lstate[ni] = lstate[ni] * alpha + tsum;
      mstate[ni] = mnew;
      #pragma unroll
      for (int f = 0; f < 8; ++f)
        #pragma unroll
        for (int r = 0; r < 4; ++r) o[f][ni][r] *= alpha;
      #pragma unroll
      for (int mi = 0; mi < 4; ++mi)
        #pragma unroll
        for (int r = 0; r < 4; ++r) p[mi][ni][r] = (short)f2bf(st[mi][ni][r]);
    }
    #pragma unroll
    for (int f = 0; f < 8; ++f)
      #pragma unroll
      for (int mi = 0; mi < 4; ++mi) {
        shortx4 vt;
        #pragma unroll
        for (int j = 0; j < 4; ++j)
          vt[j] = (short)Vp[(kt * 64 + mi * 16 + lg * 4 + j) * NHD + f * 16 + l15];
        #pragma unroll
        for (int ni = 0; ni < 2; ++ni)
          o[f][ni] = __builtin_amdgcn_mfma_f32_16x16x16bf16_1k(vt, p[mi][ni], o[f][ni], 0, 0, 0);
      }
  }
  const float inv0 = 1.f / lstate[0], inv1 = 1.f / lstate[1];
  #pragma unroll
  for (int f = 0; f < 8; ++f)
    #pragma unroll
    for (int ni = 0; ni < 2; ++ni) {
      const float inv = ni ? inv1 : inv0;
      const int q = q0 + ni * 16 + l15;
      const int hd = f * 16 + lg * 4;
      ushortx4 ov;
      #pragma unroll
      for (int r = 0; r < 4; ++r) ov[r] = f2bf(o[f][ni][r] * inv);
      *reinterpret_cast<ushortx4*>(ctx + ((long)(b * NS + q)) * ND + h * NHD + hd) = ov;
    }
}

extern "C" void kernel_launch(void* const* d_in, const int* in_sizes, int n_in,
                              void* d_out, int out_size, void* d_ws, size_t ws_size,
                              hipStream_t stream) {
  const float* x     = (const float*)d_in[0];
  const float* w_qkv = (const float*)d_in[1];
  const float* w_o   = (const float*)d_in[2];
  char* ws = (char*)d_ws;
  if (ws_size < 369098752UL) return;
  ushort_t* xb    = (ushort_t*)(ws);
  ushort_t* wqkvb = (ushort_t*)(ws + 67108864L);
  ushort_t* wob   = (ushort_t*)(ws + 92274688L);
  ushort_t* qkvb  = (ushort_t*)(ws + 100663296L);
  ushort_t* ctxb  = (ushort_t*)(ws + 301989888L);

  const long nx = (long)NB * NS * ND;
  const long nq = 3L * ND * ND;
  const long no = (long)ND * ND;
  cast_f32_bf16<<<dim3(nx / 1024), 256, 0, stream>>>(x, xb, nx);
  cast_f32_bf16<<<dim3(nq / 1024), 256, 0, stream>>>(w_qkv, wqkvb, nq);
  cast_f32_bf16<<<dim3(no / 1024), 256, 0, stream>>>(w_o, wob, no);

  const int lds_bytes = 4 * 32768;  // 128 KiB
  (void)hipFuncSetAttribute(reinterpret_cast<const void*>(&gemm256<1>),
                            hipFuncAttributeMaxDynamicSharedMemorySize, lds_bytes);
  (void)hipFuncSetAttribute(reinterpret_cast<const void*>(&gemm256<0>),
                            hipFuncAttributeMaxDynamicSharedMemorySize, lds_bytes);

  // qkv = x @ w_qkv^T  -> permuted bf16 [3][B][H][S][HD]
  gemm256<1><<<dim3(64 * 24), 512, lds_bytes, stream>>>(xb, wqkvb, nullptr, qkvb,
                                                        NB * NS, 3 * ND, ND);
  // fused causal attention -> ctx bf16 [B][S][D]
  attn_fused<<<dim3(NB * NH), 512, 0, stream>>>(qkvb, ctxb);
  // out = ctx @ w_o^T  (fp32)
  gemm256<0><<<dim3(64 * 8), 512, lds_bytes, stream>>>(ctxb, wob, (float*)d_out, nullptr,
                                                       NB * NS, ND, ND);
}

// Round 5
// 705.821 us; speedup vs baseline: 1.3135x; 1.0001x over previous
//
#include <hip/hip_runtime.h>

#define NB 64
#define NS 256
#define ND 2048
#define NH 16
#define NHD 128

typedef unsigned short ushort_t;
typedef __attribute__((ext_vector_type(8))) __bf16 bf16x8;
typedef __attribute__((ext_vector_type(4))) short shortx4;
typedef __attribute__((ext_vector_type(4))) float f32x4;
typedef __attribute__((ext_vector_type(4))) unsigned short ushortx4;

__device__ __forceinline__ unsigned short f2bf(float f) {
  union { float f; unsigned int u; } v; v.f = f;
  unsigned int r = v.u + 0x7FFFu + ((v.u >> 16) & 1u);
  return (unsigned short)(r >> 16);
}

__device__ __forceinline__ void gload16(const void* g, void* l) {
  __builtin_amdgcn_global_load_lds(
      (__attribute__((address_space(1))) void*)(void*)(g),
      (__attribute__((address_space(3))) void*)(l), 16, 0, 0);
}

__global__ void cast_f32_bf16(const float* __restrict__ in, ushort_t* __restrict__ out, long n) {
  long i = ((long)blockIdx.x * blockDim.x + threadIdx.x) * 4;
  if (i + 3 < n) {
    float4 v = *reinterpret_cast<const float4*>(in + i);
    ushortx4 o;
    o.x = f2bf(v.x); o.y = f2bf(v.y); o.z = f2bf(v.z); o.w = f2bf(v.w);
    *reinterpret_cast<ushortx4*>(out + i) = o;
  }
}

// ---------------------------------------------------------------------------
// 256x256 tile GEMM, BK=32, 8 waves (2M x 4N), 4-buffer LDS ring.
// T19 weave: next-tile ds_reads (12) + stage gloads (4) woven into the
// 32-MFMA cluster via sched_group_barrier ladder: 8 x {MFMA 4, DS_READ 2,
// VMEM 1}, keeping the LDS queue shallow so reads drain UNDER the MFMAs.
// vmcnt ledger (counted, never 0 in steady state):
//   prologue: 12 gloads (bufs 0,1,2); vmcnt(8)=buf0; frag reads buf0;
//   vmcnt(4)=buf1 landed  <-- ROUND-4 FIX: this wait was dropped in round 3,
//   letting TILE(0)'s ds_reads of buf1 race the staging DMA (absmax 0.24).
//   TILE(t) end: vmcnt(4) drains tile t+2's stage before TILE(t+1) reads it.
// Pre-MFMA wait: lgkmcnt(0) on tile-old reads, fenced per rule #18.
// T2 swizzle, T5 setprio, T1 bijective XCD swizzle unchanged.
// C[m,n] = sum_k A[m,k]*Bt[n,k].  MODE 0: fp32 C.  MODE 1: bf16 permuted qkv.
// ---------------------------------------------------------------------------
template<int MODE>
__global__ __launch_bounds__(512, 2) void gemm256(const ushort_t* __restrict__ A,
                                                  const ushort_t* __restrict__ Bt,
                                                  float* __restrict__ Cf,
                                                  ushort_t* __restrict__ Cq,
                                                  int M, int N, int K) {
  extern __shared__ char smem[];   // 4 bufs * 32768B; A at +0 (16KB), B at +16384
  const int tid = threadIdx.x;
  const int wv = tid >> 6, lane = tid & 63;
  const int l15 = lane & 15, lg = lane >> 4;
  const int wm = wv >> 2, wn = wv & 3;     // 2 x 4 wave grid; wave tile 128x64

  // T1: bijective XCD-aware block swizzle
  const int nbn = N >> 8;
  const int nwg = (M >> 8) * nbn;
  const int bid = blockIdx.x;
  const int q8 = nwg >> 3, r8 = nwg & 7;
  const int xcd = bid & 7, lin = bid >> 3;
  const int wg = (xcd < r8 ? xcd * (q8 + 1) : r8 * (q8 + 1) + (xcd - r8) * q8) + lin;
  const int m0 = (wg / nbn) << 8;
  const int n0 = (wg % nbn) << 8;

  // staging source (per-lane, pre-swizzled; LDS dest stays linear)
  const int srow = wv * 16 + (lane >> 2);
  const int sce = ((lane & 3) * 8) ^ (((srow >> 1) & 3) << 3);  // elems
  const ushort_t* pa0 = A  + (long)(m0 + srow) * K + sce;        // rows 0..127
  const ushort_t* pa1 = pa0 + (long)128 * K;                     // rows 128..255
  const ushort_t* pb0 = Bt + (long)(n0 + srow) * K + sce;
  const ushort_t* pb1 = pb0 + (long)128 * K;

  // ds_read byte-XOR constant
  const int c = (lg * 16) ^ (((l15 >> 1) & 3) << 4);

  f32x4 acc[8][4] = {};
  const int nkt = K >> 5;          // assumes nkt >= 4 and even (K=2048 -> 64)

  bf16x8 faA[8], faB[4], fbA[8], fbB[4];

  // prologue: stage tiles 0,1,2 -> bufs 0,1,2
  #pragma unroll
  for (int tt = 0; tt < 3; ++tt) {
    char* d = smem + tt * 32768 + wv * 1024;
    const long ko = (long)tt * 32;
    gload16(pa0 + ko, d);
    gload16(pa1 + ko, d + 8192);
    gload16(pb0 + ko, d + 16384);
    gload16(pb1 + ko, d + 24576);
  }
  asm volatile("s_waitcnt vmcnt(8)" ::: "memory");   // buf0 landed
  __builtin_amdgcn_s_barrier();
  __builtin_amdgcn_sched_barrier(0);
  // pre-loop: issue frag reads for tile 0 (drained by TILE(0)'s lgkmcnt(0))
  #pragma unroll
  for (int i = 0; i < 8; ++i)
    faA[i] = *reinterpret_cast<const bf16x8*>(smem + (wm * 128 + i * 16 + l15) * 64 + c);
  #pragma unroll
  for (int j = 0; j < 4; ++j)
    faB[j] = *reinterpret_cast<const bf16x8*>(smem + 16384 + (wn * 64 + j * 16 + l15) * 64 + c);
  // ROUND-4 FIX: buf1 must be landed before TILE(0)'s body reads it.
  asm volatile("s_waitcnt vmcnt(4)" ::: "memory");   // buf1 landed (buf2 in flight)

#define TILE(T_, CA_, CB_, NA_, NB_)                                           \
  {                                                                            \
    const int t_ = (T_);                                                       \
    __builtin_amdgcn_s_barrier();                                              \
    asm volatile("s_waitcnt lgkmcnt(0)" ::: "memory");                         \
    __builtin_amdgcn_sched_barrier(0);                                         \
    __builtin_amdgcn_s_setprio(1);                                             \
    if (t_ + 1 < nkt) {                                                        \
      const char* rb = smem + ((t_ + 1) & 3) * 32768;                          \
      _Pragma("unroll")                                                        \
      for (int i = 0; i < 8; ++i)                                              \
        NA_[i] = *reinterpret_cast<const bf16x8*>(rb + (wm * 128 + i * 16 + l15) * 64 + c); \
      _Pragma("unroll")                                                        \
      for (int j = 0; j < 4; ++j)                                              \
        NB_[j] = *reinterpret_cast<const bf16x8*>(rb + 16384 + (wn * 64 + j * 16 + l15) * 64 + c); \
    }                                                                          \
    if (t_ + 3 < nkt) {                                                        \
      char* d = smem + ((t_ + 3) & 3) * 32768 + wv * 1024;                     \
      const long ko = (long)(t_ + 3) * 32;                                     \
      gload16(pa0 + ko, d);                                                    \
      gload16(pa1 + ko, d + 8192);                                             \
      gload16(pb0 + ko, d + 16384);                                            \
      gload16(pb1 + ko, d + 24576);                                            \
    }                                                                          \
    _Pragma("unroll")                                                          \
    for (int i = 0; i < 8; ++i)                                                \
      _Pragma("unroll")                                                        \
      for (int j = 0; j < 4; ++j)                                              \
        acc[i][j] = __builtin_amdgcn_mfma_f32_16x16x32_bf16(CA_[i], CB_[j], acc[i][j], 0, 0, 0); \
    /* T19 ladder: weave 2 ds_reads + 1 vmem between every 4 MFMAs */          \
    _Pragma("unroll")                                                          \
    for (int g = 0; g < 8; ++g) {                                              \
      __builtin_amdgcn_sched_group_barrier(0x008, 4, 0);                       \
      if (g < 6) __builtin_amdgcn_sched_group_barrier(0x100, 2, 0);            \
      if (g < 4) __builtin_amdgcn_sched_group_barrier(0x010, 1, 0);            \
    }                                                                          \
    __builtin_amdgcn_s_setprio(0);                                             \
    __builtin_amdgcn_sched_barrier(0);                                         \
    if (t_ + 3 < nkt) asm volatile("s_waitcnt vmcnt(4)" ::: "memory");         \
    else              asm volatile("s_waitcnt vmcnt(0)" ::: "memory");         \
  }

  for (int t = 0; t < nkt; t += 2) {
    TILE(t,     faA, faB, fbA, fbB);
    TILE(t + 1, fbA, fbB, faA, faB);
  }
#undef TILE

  // epilogue: D frag col = l15 (n), rows = lg*4 + r
  #pragma unroll
  for (int k = 0; k < 8; ++k) {
    const int mrow = m0 + wm * 128 + k * 16 + lg * 4;
    #pragma unroll
    for (int j = 0; j < 4; ++j) {
      const int n = n0 + wn * 64 + j * 16 + l15;
      #pragma unroll
      for (int r = 0; r < 4; ++r) {
        const int m = mrow + r;
        const float v = acc[k][j][r];
        if (MODE == 0) {
          Cf[(long)m * N + n] = v;
        } else {
          const int tq = n >> 11, hh = (n >> 7) & 15, hd = n & 127;
          const int b = m >> 8, s = m & 255;
          Cq[((((long)tq * NB + b) * NH + hh) * NS + s) * NHD + hd] = f2bf(v);
        }
      }
    }
  }
}

// One block per (b,h); 8 waves x 32 Q-rows. Flash-style online softmax.
__global__ __launch_bounds__(512) void attn_fused(const ushort_t* __restrict__ qkv,
                                                  ushort_t* __restrict__ ctx) {
  const int bh = blockIdx.x;
  const int b = bh >> 4, h = bh & 15;
  const int wave = threadIdx.x >> 6, lane = threadIdx.x & 63;
  const int l15 = lane & 15, lg = lane >> 4;
  const long head_off = ((long)(b * NH + h)) * (NS * NHD);
  const ushort_t* Qp = qkv + head_off;
  const ushort_t* Kp = qkv + (long)NB * NH * NS * NHD + head_off;
  const ushort_t* Vp = qkv + 2L * NB * NH * NS * NHD + head_off;
  const int q0 = wave * 32;

  bf16x8 qf[2][4];
  #pragma unroll
  for (int ni = 0; ni < 2; ++ni)
    #pragma unroll
    for (int kk = 0; kk < 4; ++kk)
      qf[ni][kk] = *reinterpret_cast<const bf16x8*>(Qp + (q0 + ni * 16 + l15) * NHD + kk * 32 + lg * 8);

  f32x4 o[8][2] = {};
  float mstate[2] = {-1e30f, -1e30f};
  float lstate[2] = {0.f, 0.f};
  const float scale = 0.08838834764831845f;
  const int ntiles = (q0 + 32 + 63) >> 6;

  for (int kt = 0; kt < ntiles; ++kt) {
    f32x4 st[4][2] = {};
    #pragma unroll
    for (int kk = 0; kk < 4; ++kk) {
      bf16x8 kf[4];
      #pragma unroll
      for (int mi = 0; mi < 4; ++mi)
        kf[mi] = *reinterpret_cast<const bf16x8*>(Kp + (kt * 64 + mi * 16 + l15) * NHD + kk * 32 + lg * 8);
      #pragma unroll
      for (int mi = 0; mi < 4; ++mi)
        #pragma unroll
        for (int ni = 0; ni < 2; ++ni)
          st[mi][ni] = __builtin_amdgcn_mfma_f32_16x16x32_bf16(kf[mi], qf[ni][kk], st[mi][ni], 0, 0, 0);
    }
    const bool last = (kt == ntiles - 1);
    #pragma unroll
    for (int mi = 0; mi < 4; ++mi)
      #pragma unroll
      for (int ni = 0; ni < 2; ++ni)
        #pragma unroll
        for (int r = 0; r < 4; ++r) {
          const int kc = kt * 64 + mi * 16 + lg * 4 + r;
          const int q = q0 + ni * 16 + l15;
          float v = st[mi][ni][r] * scale;
          if (last && kc > q) v = -1e30f;
          st[mi][ni][r] = v;
        }
    shortx4 p[4][2];
    #pragma unroll
    for (int ni = 0; ni < 2; ++ni) {
      float tmax = -1e30f;
      #pragma unroll
      for (int mi = 0; mi < 4; ++mi)
        #pragma unroll
        for (int r = 0; r < 4; ++r) tmax = fmaxf(tmax, st[mi][ni][r]);
      tmax = fmaxf(tmax, __shfl_xor(tmax, 16, 64));
      tmax = fmaxf(tmax, __shfl_xor(tmax, 32, 64));
      const float mnew = fmaxf(mstate[ni], tmax);
      const float alpha = __expf(mstate[ni] - mnew);
      float tsum = 0.f;
      #pragma unroll
      for (int mi = 0; mi < 4; ++mi)
        #pragma unroll
        for (int r = 0; r < 4; ++r) {
          const float pe = __expf(st[mi][ni][r] - mnew);
          st[mi][ni][r] = pe;
          tsum += pe;
        }
      tsum += __shfl_xor(tsum, 16, 64);
      tsum += __shfl_xor(tsum, 32, 64);
      lstate[ni] = lstate[ni] * alpha + tsum;
      mstate[ni] = mnew;
      #pragma unroll
      for (int f = 0; f < 8; ++f)
        #pragma unroll
        for (int r = 0; r < 4; ++r) o[f][ni][r] *= alpha;
      #pragma unroll
      for (int mi = 0; mi < 4; ++mi)
        #pragma unroll
        for (int r = 0; r < 4; ++r) p[mi][ni][r] = (short)f2bf(st[mi][ni][r]);
    }
    #pragma unroll
    for (int f = 0; f < 8; ++f)
      #pragma unroll
      for (int mi = 0; mi < 4; ++mi) {
        shortx4 vt;
        #pragma unroll
        for (int j = 0; j < 4; ++j)
          vt[j] = (short)Vp[(kt * 64 + mi * 16 + lg * 4 + j) * NHD + f * 16 + l15];
        #pragma unroll
        for (int ni = 0; ni < 2; ++ni)
          o[f][ni] = __builtin_amdgcn_mfma_f32_16x16x16bf16_1k(vt, p[mi][ni], o[f][ni], 0, 0, 0);
      }
  }
  const float inv0 = 1.f / lstate[0], inv1 = 1.f / lstate[1];
  #pragma unroll
  for (int f = 0; f < 8; ++f)
    #pragma unroll
    for (int ni = 0; ni < 2; ++ni) {
      const float inv = ni ? inv1 : inv0;
      const int q = q0 + ni * 16 + l15;
      const int hd = f * 16 + lg * 4;
      ushortx4 ov;
      #pragma unroll
      for (int r = 0; r < 4; ++r) ov[r] = f2bf(o[f][ni][r] * inv);
      *reinterpret_cast<ushortx4*>(ctx + ((long)(b * NS + q)) * ND + h * NHD + hd) = ov;
    }
}

extern "C" void kernel_launch(void* const* d_in, const int* in_sizes, int n_in,
                              void* d_out, int out_size, void* d_ws, size_t ws_size,
                              hipStream_t stream) {
  const float* x     = (const float*)d_in[0];
  const float* w_qkv = (const float*)d_in[1];
  const float* w_o   = (const float*)d_in[2];
  char* ws = (char*)d_ws;
  if (ws_size < 369098752UL) return;
  ushort_t* xb    = (ushort_t*)(ws);
  ushort_t* wqkvb = (ushort_t*)(ws + 67108864L);
  ushort_t* wob   = (ushort_t*)(ws + 92274688L);
  ushort_t* qkvb  = (ushort_t*)(ws + 100663296L);
  ushort_t* ctxb  = (ushort_t*)(ws + 301989888L);

  const long nx = (long)NB * NS * ND;
  const long nq = 3L * ND * ND;
  const long no = (long)ND * ND;
  cast_f32_bf16<<<dim3(nx / 1024), 256, 0, stream>>>(x, xb, nx);
  cast_f32_bf16<<<dim3(nq / 1024), 256, 0, stream>>>(w_qkv, wqkvb, nq);
  cast_f32_bf16<<<dim3(no / 1024), 256, 0, stream>>>(w_o, wob, no);

  const int lds_bytes = 4 * 32768;  // 128 KiB
  (void)hipFuncSetAttribute(reinterpret_cast<const void*>(&gemm256<1>),
                            hipFuncAttributeMaxDynamicSharedMemorySize, lds_bytes);
  (void)hipFuncSetAttribute(reinterpret_cast<const void*>(&gemm256<0>),
                            hipFuncAttributeMaxDynamicSharedMemorySize, lds_bytes);

  // qkv = x @ w_qkv^T  -> permuted bf16 [3][B][H][S][HD]
  gemm256<1><<<dim3(64 * 24), 512, lds_bytes, stream>>>(xb, wqkvb, nullptr, qkvb,
                                                        NB * NS, 3 * ND, ND);
  // fused causal attention -> ctx bf16 [B][S][D]
  attn_fused<<<dim3(NB * NH), 512, 0, stream>>>(qkvb, ctxb);
  // out = ctx @ w_o^T  (fp32)
  gemm256<0><<<dim3(64 * 8), 512, lds_bytes, stream>>>(ctxb, wob, (float*)d_out, nullptr,
                                                       NB * NS, ND, ND);
}